// Round 5
// baseline (1010.899 us; speedup 1.0000x reference)
//
#include <hip/hip_runtime.h>
#include <cmath>

// n = m = 8192, d = 64, reg = 0.05, 20 Sinkhorn iterations
#define NPTS 8192
#define DIM  64
#define NPART 32   // col-blocks of 256 -> 32 partial sums per row
#define LOG2E 1.4426950408889634f
#define LA2   -13.0f   // log2(1/8192) exactly

typedef short s16x8  __attribute__((ext_vector_type(8)));   // 8 bf16
typedef float f32x16 __attribute__((ext_vector_type(16)));  // MFMA 32x32 acc

typedef __attribute__((address_space(1))) const unsigned char g8_t;
typedef __attribute__((address_space(3))) unsigned char l8_t;

#if __has_builtin(__builtin_amdgcn_exp2f)
__device__ __forceinline__ float exp2_fast(float x) { return __builtin_amdgcn_exp2f(x); }
#else
__device__ __forceinline__ float exp2_fast(float x) { return exp2f(x); }
#endif
#if __has_builtin(__builtin_amdgcn_logf)
__device__ __forceinline__ float log2_fast(float x) { return __builtin_amdgcn_logf(x); }
#else
__device__ __forceinline__ float log2_fast(float x) { return log2f(x); }
#endif

__device__ __forceinline__ unsigned short f2bf(float x) {
  unsigned u = __float_as_uint(x);
  return (unsigned short)((u + 0x7FFFu + ((u >> 16) & 1u)) >> 16);
}
__device__ __forceinline__ float bf2f(unsigned short b) {
  return __uint_as_float(((unsigned)b) << 16);
}

// ---------------------------------------------------------------------------
// prep: bf16 hi/lo split + squared row norms; init scal/out. one wave per row.
// ---------------------------------------------------------------------------
__global__ __launch_bounds__(256) void prep_kernel(
    const float* __restrict__ XP, const float* __restrict__ XQ,
    unsigned short* __restrict__ Phi, unsigned short* __restrict__ Plo,
    unsigned short* __restrict__ Qhi, unsigned short* __restrict__ Qlo,
    float* __restrict__ x2, float* __restrict__ y2,
    float* __restrict__ scal, float* __restrict__ out) {
  int gid  = blockIdx.x * 256 + threadIdx.x;
  int lane = threadIdx.x & 63;
  int row  = gid >> 6;            // 0..16383: P rows then Q rows (wave-uniform)
  int isP  = row < NPTS;
  int r    = row & (NPTS - 1);
  const float* X = isP ? XP : XQ;
  float x = X[r * DIM + lane];
  unsigned short h = f2bf(x);
  (isP ? Phi : Qhi)[r * DIM + lane] = h;
  (isP ? Plo : Qlo)[r * DIM + lane] = f2bf(x - bf2f(h));
  float s = x * x;
  for (int off = 32; off; off >>= 1) s += __shfl_down(s, off, 64);
  if (lane == 0) (isP ? x2 : y2)[r] = s;
  if (gid == 0) { ((unsigned*)scal)[0] = 0u; out[0] = 0.0f; }
}

// ---------------------------------------------------------------------------
// pass_kernel<MODE, FIRST, RS, MINW>: sweep a (128*RS rows x 256 cols) tile.
// B panel (256 rows x 64 feats bf16) staged ONCE via async global_load_lds,
// xor-swizzled; exactly one __syncthreads in the whole kernel body.
// Wave w owns rows [w*32*RS, w*32*RS + 32*RS): RS MFMA chains share each B frag.
// MODE 0: cmax = max d2 (hi dot)                 -> atomicMax(uint) outScalar
// MODE 1: row sums of 2^(C2L*dot + b_j)          -> plain store outPart[gy][i]
//    b_j = FIRST ? -invC*y2_j*log2e : LA2 - log2(sum_gy colPart[gy][j])
//    (row-norm terms cancel exactly: u_i - invC*x2_i = LA2 - log2(rowsum_i))
// MODE 2: out += d2 * 2^(C2L*dot + bu_i + bv_j)  -> atomicAdd outScalar
// C/D layout (m74/m101): col = lane&31, row = (reg&3) + 8*(reg>>2) + 4*(lane>>5)
// ---------------------------------------------------------------------------
template <int MODE, bool FIRST, int RS, int MINW>
__global__ __launch_bounds__(256, MINW) void pass_kernel(
    const unsigned short* __restrict__ Ahi, const unsigned short* __restrict__ Alo,
    const unsigned short* __restrict__ Bhi,
    const float* __restrict__ x2row, const float* __restrict__ y2col,
    const float* __restrict__ colPart, const float* __restrict__ rowPart,
    const unsigned* __restrict__ cmaxBits,
    float* __restrict__ outPart, float* __restrict__ outScalar) {
  __shared__ short sB[256 * DIM];   // 32 KB panel, xor-swizzled 16B chunks
  __shared__ float sCol[256];       // per-col log2-domain base (modes 1,2)
  __shared__ float sY2[256];        // modes 0,2
  __shared__ float sX2[128];        // modes 0,2 (RS=1 there)
  __shared__ float sU2[128];        // mode 2
  __shared__ float sRed[4];

  const int t  = threadIdx.x;
  const int w  = t >> 6;
  const int l  = t & 63;
  const int g  = l >> 5;
  const int ln = l & 31;
  const int i0 = blockIdx.x * 128 * RS;
  const int j0 = blockIdx.y * 256;

  float invC = 0.f, C2L = 0.f;
  if constexpr (MODE != 0) {
    float cmax = __uint_as_float(*cmaxBits);
    invC = 1.0f / (0.05f * cmax);
    C2L  = 2.0f * invC * LOG2E;
  }

  // async stage: physical slot s = w*512 + c*64 + l holds
  // (row = s>>3, chunk = (s&7)^(row&7)); +64 slots = +1024 B exactly.
  {
    int s   = w * 512 + l;
    int row = s >> 3;
    int cc  = (s & 7) ^ (row & 7);
    const unsigned char* g0 =
        (const unsigned char*)(Bhi + (size_t)j0 * DIM) + row * 128 + cc * 16;
#pragma unroll
    for (int c = 0; c < 8; ++c)
      __builtin_amdgcn_global_load_lds(
          (g8_t*)(g0 + c * 1024),
          (l8_t*)((unsigned char*)sB + w * 8192 + c * 1024), 16, 0, 0);
  }

  // A fragments: lane holds A[m=ln][k = ks*16 + g*8 + j]
  s16x8 a_hi[RS][4], a_lo[RS][4];
#pragma unroll
  for (int s = 0; s < RS; ++s) {
    const unsigned short* pa =
        Ahi + (size_t)(i0 + (w * RS + s) * 32 + ln) * DIM + g * 8;
#pragma unroll
    for (int ks = 0; ks < 4; ++ks) a_hi[s][ks] = *(const s16x8*)(pa + ks * 16);
    if constexpr (MODE == 2) {
      const unsigned short* pb =
          Alo + (size_t)(i0 + (w * RS + s) * 32 + ln) * DIM + g * 8;
#pragma unroll
      for (int ks = 0; ks < 4; ++ks) a_lo[s][ks] = *(const s16x8*)(pb + ks * 16);
    }
  }

  // per-col base / norms (one element per thread)
  {
    int j = j0 + t;
    if constexpr (MODE == 0) {
      sY2[t] = y2col[j];
    } else if constexpr (MODE == 1) {
      if constexpr (FIRST) {
        sCol[t] = -invC * y2col[j] * LOG2E;
      } else {
        float s = 0.f;
#pragma unroll
        for (int gy = 0; gy < NPART; ++gy) s += colPart[gy * NPTS + j];
        sCol[t] = LA2 - log2_fast(s);
      }
    } else {
      float s = 0.f;
#pragma unroll
      for (int gy = 0; gy < NPART; ++gy) s += colPart[gy * NPTS + j];
      sCol[t] = LA2 - log2_fast(s);
      sY2[t] = y2col[j];
    }
  }
  if constexpr (MODE != 1) {
    if (t < 128) {
      sX2[t] = x2row[i0 + t];
      if constexpr (MODE == 2) {
        float s = 0.f;
#pragma unroll
        for (int gy = 0; gy < NPART; ++gy) s += rowPart[gy * NPTS + i0 + t];
        sU2[t] = LA2 - log2_fast(s);
      }
    }
  }
  __syncthreads();   // drains async stage (vmcnt) + LDS writes

  float x2r[16], u2r[16];
  if constexpr (MODE != 1) {
#pragma unroll
    for (int r = 0; r < 16; ++r) {
      int ri = w * 32 + (r & 3) + 8 * (r >> 2) + 4 * g;
      x2r[r] = sX2[ri];
      if constexpr (MODE == 2) u2r[r] = sU2[ri];
    }
  }

  float racc[RS][16];
#pragma unroll
  for (int s = 0; s < RS; ++s)
#pragma unroll
    for (int r = 0; r < 16; ++r) racc[s][r] = 0.f;
  float accS = 0.f;

#pragma unroll 2
  for (int ct = 0; ct < 8; ++ct) {
    const int n = ct * 32 + ln;       // panel column this lane epilogues
    s16x8 b[4];
#pragma unroll
    for (int ks = 0; ks < 4; ++ks)
      b[ks] = *(const s16x8*)(sB + n * DIM + (((ks * 2 + g) ^ (ln & 7)) * 8));

    if constexpr (MODE == 1) {
      float bb = sCol[n];
#pragma unroll
      for (int s = 0; s < RS; ++s) {
        f32x16 acc;
#pragma unroll
        for (int r = 0; r < 16; ++r) acc[r] = 0.f;
#pragma unroll
        for (int ks = 0; ks < 4; ++ks)
          acc = __builtin_amdgcn_mfma_f32_32x32x16_bf16(a_hi[s][ks], b[ks], acc, 0, 0, 0);
#pragma unroll
        for (int r = 0; r < 16; ++r)
          racc[s][r] += exp2_fast(fmaf(C2L, acc[r], bb));
      }
    } else if constexpr (MODE == 0) {
      f32x16 acc;
#pragma unroll
      for (int r = 0; r < 16; ++r) acc[r] = 0.f;
#pragma unroll
      for (int ks = 0; ks < 4; ++ks)
        acc = __builtin_amdgcn_mfma_f32_32x32x16_bf16(a_hi[0][ks], b[ks], acc, 0, 0, 0);
      float y2v = sY2[n];
#pragma unroll
      for (int r = 0; r < 16; ++r)
        accS = fmaxf(accS, fmaf(-2.0f, acc[r], x2r[r] + y2v));
    } else {
      f32x16 acc, acc2;
#pragma unroll
      for (int r = 0; r < 16; ++r) { acc[r] = 0.f; acc2[r] = 0.f; }
#pragma unroll
      for (int ks = 0; ks < 4; ++ks)
        acc = __builtin_amdgcn_mfma_f32_32x32x16_bf16(a_hi[0][ks], b[ks], acc, 0, 0, 0);
#pragma unroll
      for (int ks = 0; ks < 4; ++ks)
        acc2 = __builtin_amdgcn_mfma_f32_32x32x16_bf16(a_lo[0][ks], b[ks], acc2, 0, 0, 0);
      float y2v = sY2[n];
      float bb  = sCol[n];
#pragma unroll
      for (int r = 0; r < 16; ++r) {
        float dot = acc[r] + acc2[r];
        float d2  = fmaxf(fmaf(-2.0f, dot, x2r[r] + y2v), 0.0f);
        accS = fmaf(d2, exp2_fast(fmaf(C2L, dot, u2r[r] + bb)), accS);
      }
    }
  }

  if constexpr (MODE == 1) {
    // reduce each acc row over its 32 cols (stays in the g-half), plain store
#pragma unroll
    for (int s = 0; s < RS; ++s)
#pragma unroll
      for (int r = 0; r < 16; ++r) {
        float v = racc[s][r];
        v += __shfl_xor(v, 1, 64);
        v += __shfl_xor(v, 2, 64);
        v += __shfl_xor(v, 4, 64);
        v += __shfl_xor(v, 8, 64);
        v += __shfl_xor(v, 16, 64);
        if (ln == 0)
          outPart[blockIdx.y * NPTS + i0 + (w * RS + s) * 32 +
                  (r & 3) + 8 * (r >> 2) + 4 * g] = v;
      }
  } else {
    float v = accS;
#pragma unroll
    for (int off = 1; off < 64; off <<= 1) {
      float o = __shfl_xor(v, off, 64);
      v = (MODE == 0) ? fmaxf(v, o) : (v + o);
    }
    if (l == 0) sRed[w] = v;
    __syncthreads();
    if (t == 0) {
      float r0 = (MODE == 0) ? fmaxf(fmaxf(sRed[0], sRed[1]), fmaxf(sRed[2], sRed[3]))
                             : (sRed[0] + sRed[1] + sRed[2] + sRed[3]);
      if constexpr (MODE == 0)
        atomicMax((unsigned*)outScalar, __float_as_uint(r0));
      else
        atomicAdd(outScalar, r0);
    }
  }
}

// ---------------------------------------------------------------------------
extern "C" void kernel_launch(void* const* d_in, const int* in_sizes, int n_in,
                              void* d_out, int out_size, void* d_ws, size_t ws_size,
                              hipStream_t stream) {
  (void)in_sizes; (void)n_in; (void)out_size; (void)ws_size;
  const float* XP = (const float*)d_in[0];
  const float* XQ = (const float*)d_in[1];
  float* out = (float*)d_out;

  float* ws    = (float*)d_ws;
  float* x2    = ws;                        // 8192
  float* y2    = ws + 8192;                 // 8192
  float* partU = ws + 16384;                // 32 x 8192 (u-pass row sums)
  float* partV = partU + NPART * NPTS;      // 32 x 8192 (v-pass row sums)
  float* scal  = partV + NPART * NPTS;      // [0] = cmax bits (16 reserved)
  unsigned short* Phi = (unsigned short*)(scal + 16);
  unsigned short* Plo = Phi + (size_t)NPTS * DIM;
  unsigned short* Qhi = Plo + (size_t)NPTS * DIM;
  unsigned short* Qlo = Qhi + (size_t)NPTS * DIM;   // total ws ~6.4 MB

  const unsigned* cmaxB = (const unsigned*)scal;
  dim3 gridH(NPTS / 256, NPTS / 256);       // (32, 32) hot mode1, RS=2
  dim3 gridW(NPTS / 128, NPTS / 256);       // (64, 32) modes 0,2, RS=1

  prep_kernel<<<NPTS * 2 * DIM / 256, 256, 0, stream>>>(
      XP, XQ, Phi, Plo, Qhi, Qlo, x2, y2, scal, out);

  // Cmax (hi-only: |err| ~1e-4 relative, shifts effective reg negligibly)
  pass_kernel<0, false, 1, 4><<<gridW, 256, 0, stream>>>(
      Phi, nullptr, Qhi, x2, y2, nullptr, nullptr, cmaxB, nullptr, scal);

  // iter 1: u-pass with v = 0 (base from y2), then v-pass from partU
  pass_kernel<1, true, 2, 4><<<gridH, 256, 0, stream>>>(
      Phi, nullptr, Qhi, nullptr, y2, nullptr, nullptr, cmaxB, partU, nullptr);
  pass_kernel<1, false, 2, 4><<<gridH, 256, 0, stream>>>(
      Qhi, nullptr, Phi, nullptr, nullptr, partU, nullptr, cmaxB, partV, nullptr);

  for (int it = 1; it < 20; ++it) {
    pass_kernel<1, false, 2, 4><<<gridH, 256, 0, stream>>>(
        Phi, nullptr, Qhi, nullptr, nullptr, partV, nullptr, cmaxB, partU, nullptr);
    pass_kernel<1, false, 2, 4><<<gridH, 256, 0, stream>>>(
        Qhi, nullptr, Phi, nullptr, nullptr, partU, nullptr, cmaxB, partV, nullptr);
  }

  // final: sum C * plan (hi+lo dot for C accuracy)
  pass_kernel<2, false, 1, 2><<<gridW, 256, 0, stream>>>(
      Phi, Plo, Qhi, x2, y2, partV, partU, cmaxB, nullptr, out);
}